// Round 1
// baseline (3634.284 us; speedup 1.0000x reference)
//
#include <hip/hip_runtime.h>

#define SLOPE 0.2f

__device__ __forceinline__ unsigned fenc(float f) {
    unsigned u = __float_as_uint(f);
    return (u & 0x80000000u) ? ~u : (u | 0x80000000u);
}
__device__ __forceinline__ float fdec(unsigned u) {
    return (u & 0x80000000u) ? __uint_as_float(u & 0x7fffffffu) : __uint_as_float(~u);
}

// ---- Pass A: layer-1 node projections: f_ni [N,64], f_nj [N,64], ft1 [N,256]
__global__ __launch_bounds__(256) void k_nodeproj1(
    const float* __restrict__ nf, const float* __restrict__ Wni,
    const float* __restrict__ Wnj, const float* __restrict__ Wnode,
    const float* __restrict__ bnode,
    float* __restrict__ fni, float* __restrict__ fnj, float* __restrict__ ft1)
{
    __shared__ float s[128];
    const int node = blockIdx.x;
    const int t = threadIdx.x;
    if (t < 128) s[t] = nf[(size_t)node * 128 + t];
    __syncthreads();
    float acc = bnode[t];
#pragma unroll 4
    for (int k = 0; k < 128; k++) acc = fmaf(s[k], Wnode[k * 256 + t], acc);
    ft1[(size_t)node * 256 + t] = acc;
    if (t < 128) {
        const float* __restrict__ W = (t < 64) ? Wni : Wnj;
        const int j = t & 63;
        float a = 0.f;
#pragma unroll 4
        for (int k = 0; k < 128; k++) a = fmaf(s[k], W[k * 64 + j], a);
        if (t < 64) fni[(size_t)node * 64 + j] = a;
        else        fnj[(size_t)node * 64 + j] = a;
    }
}

// ---- Pass B: layer-1 edge pass. One wave (64 lanes) per edge.
// f[lane] = f_ni[src][lane] + ef@W1_fij[:,lane] + f_nj[dst][lane] + b; leaky
// e1[e][h] = dot(f[h*16:+16], attn1[h]); fe[e][c] = 0.25*sum_h relu(f[h*16+c])
__global__ __launch_bounds__(256) void k_edge1(
    const float* __restrict__ ef, const int* __restrict__ src,
    const int* __restrict__ dst, const float* __restrict__ Wfij,
    const float* __restrict__ bedge, const float* __restrict__ attn,
    const float* __restrict__ fni, const float* __restrict__ fnj,
    float* __restrict__ e1, float* __restrict__ fe, unsigned* __restrict__ m1,
    int E)
{
    const int lane = threadIdx.x & 63;
    const int edge = blockIdx.x * 4 + (threadIdx.x >> 6);
    if (edge >= E) return;
    const int s = src[edge], d = dst[edge];
    float v = (lane < 32) ? ef[(size_t)edge * 32 + lane] : 0.f;
    float f = fni[(size_t)s * 64 + lane] + fnj[(size_t)d * 64 + lane] + bedge[lane];
#pragma unroll
    for (int k = 0; k < 32; k++)
        f = fmaf(__shfl(v, k, 64), Wfij[k * 64 + lane], f);
    const float fl = (f > 0.f) ? f : SLOPE * f;
    // per-head attention logit (reduce within each 16-lane group)
    const int h = lane >> 4;
    float p = fl * attn[h * 16 + (lane & 15)];
    p += __shfl_xor(p, 1, 64);
    p += __shfl_xor(p, 2, 64);
    p += __shfl_xor(p, 4, 64);
    p += __shfl_xor(p, 8, 64);
    if ((lane & 15) == 0) {
        e1[(size_t)edge * 4 + h] = p;
        atomicMax(&m1[(size_t)d * 4 + h], fenc(p));
    }
    // fe = mean over heads of relu(leaky(f)) == mean over heads of max(f,0)
    float r = fmaxf(fl, 0.f);
    r += __shfl_xor(r, 16, 64);
    r += __shfl_xor(r, 32, 64);
    if (lane < 16) fe[(size_t)edge * 16 + lane] = 0.25f * r;
}

// ---- softmax denominator: s[dst,h] += exp(e - m[dst,h])  (shared by both layers)
__global__ __launch_bounds__(256) void k_soft(
    const int* __restrict__ dst, const float* __restrict__ e,
    const unsigned* __restrict__ m, float* __restrict__ s, int E)
{
    const int i = blockIdx.x * 256 + threadIdx.x;
    if (i >= E * 4) return;
    const int ed = i >> 2, h = i & 3;
    const int d = dst[ed];
    const float a = __expf(e[i] - fdec(m[(size_t)d * 4 + h]));
    atomicAdd(&s[(size_t)d * 4 + h], a);
}

// ---- Pass C: layer-1 message passing. Wave per edge; 4 heads x 64 feats.
__global__ __launch_bounds__(256) void k_msg1(
    const int* __restrict__ src, const int* __restrict__ dst,
    const float* __restrict__ e1, const unsigned* __restrict__ m1,
    const float* __restrict__ s1, const float* __restrict__ ft1,
    float* __restrict__ out1, int E)
{
    const int lane = threadIdx.x & 63;
    const int edge = blockIdx.x * 4 + (threadIdx.x >> 6);
    if (edge >= E) return;
    const int s = src[edge], d = dst[edge];
    const float4 ev = *(const float4*)(e1 + (size_t)edge * 4);
    const uint4  mv = *(const uint4*)(m1 + (size_t)d * 4);
    const float4 sv = *(const float4*)(s1 + (size_t)d * 4);
    const float c0 = __expf(ev.x - fdec(mv.x)) / sv.x;
    const float c1 = __expf(ev.y - fdec(mv.y)) / sv.y;
    const float c2 = __expf(ev.z - fdec(mv.z)) / sv.z;
    const float c3 = __expf(ev.w - fdec(mv.w)) / sv.w;
    const float* __restrict__ fts = ft1 + (size_t)s * 256;
    float* od = out1 + (size_t)d * 256;
    atomicAdd(od + lane,       c0 * fts[lane]);
    atomicAdd(od + 64 + lane,  c1 * fts[64 + lane]);
    atomicAdd(od + 128 + lane, c2 * fts[128 + lane]);
    atomicAdd(od + 192 + lane, c3 * fts[192 + lane]);
}

// ---- Pass D: h = relu(out1).mean(heads) : [N,64]
__global__ __launch_bounds__(256) void k_headavg1(
    const float* __restrict__ out1, float* __restrict__ hbuf, int n)
{
    const int i = blockIdx.x * 256 + threadIdx.x;
    if (i >= n * 64) return;
    const int node = i >> 6, j = i & 63;
    const float* p = out1 + (size_t)node * 256;
    const float a = fmaxf(p[j], 0.f) + fmaxf(p[64 + j], 0.f) +
                    fmaxf(p[128 + j], 0.f) + fmaxf(p[192 + j], 0.f);
    hbuf[i] = 0.25f * a;
}

// ---- Pass E: layer-2 node projections. Wave per node (4 nodes/block).
__global__ __launch_bounds__(256) void k_nodeproj2(
    const float* __restrict__ hbuf, const float* __restrict__ Wni,
    const float* __restrict__ Wnj, const float* __restrict__ Wnode,
    const float* __restrict__ bnode,
    float* __restrict__ fni2, float* __restrict__ fnj2, float* __restrict__ ft2,
    int n)
{
    __shared__ float sh[4][64];
    const int lane = threadIdx.x & 63, w = threadIdx.x >> 6;
    const int node = blockIdx.x * 4 + w;
    const int nc = (node < n) ? node : (n - 1);
    const float v = hbuf[(size_t)nc * 64 + lane];
    sh[w][lane] = v;
    __syncthreads();
    float acc = bnode[lane];
#pragma unroll 4
    for (int k = 0; k < 64; k++) acc = fmaf(sh[w][k], Wnode[k * 64 + lane], acc);
    float pi[4], pj[4];
#pragma unroll
    for (int h = 0; h < 4; h++) { pi[h] = v * Wni[lane * 4 + h]; pj[h] = v * Wnj[lane * 4 + h]; }
#pragma unroll
    for (int mk = 1; mk < 64; mk <<= 1) {
#pragma unroll
        for (int h = 0; h < 4; h++) {
            pi[h] += __shfl_xor(pi[h], mk, 64);
            pj[h] += __shfl_xor(pj[h], mk, 64);
        }
    }
    if (node < n) {
        ft2[(size_t)node * 64 + lane] = acc;
        if (lane == 0) {
            *(float4*)(fni2 + (size_t)node * 4) = make_float4(pi[0], pi[1], pi[2], pi[3]);
            *(float4*)(fnj2 + (size_t)node * 4) = make_float4(pj[0], pj[1], pj[2], pj[3]);
        }
    }
}

// ---- Pass F: layer-2 edge pass. One thread per edge.
__global__ __launch_bounds__(256) void k_edge2(
    const float* __restrict__ fe, const int* __restrict__ src,
    const int* __restrict__ dst, const float* __restrict__ Wfij,
    const float* __restrict__ bedge, const float* __restrict__ attn2,
    const float* __restrict__ fni2, const float* __restrict__ fnj2,
    float* __restrict__ e2, unsigned* __restrict__ m2, int E)
{
    const int e = blockIdx.x * 256 + threadIdx.x;
    if (e >= E) return;
    const int s = src[e], d = dst[e];
    const float4 a = *(const float4*)(fni2 + (size_t)s * 4);
    const float4 b = *(const float4*)(fnj2 + (size_t)d * 4);
    float f0 = a.x + b.x + bedge[0];
    float f1 = a.y + b.y + bedge[1];
    float f2 = a.z + b.z + bedge[2];
    float f3 = a.w + b.w + bedge[3];
    const float4* fer = (const float4*)(fe + (size_t)e * 16);
    const float4 q0 = fer[0], q1 = fer[1], q2 = fer[2], q3 = fer[3];
#define FSTEP(fv, kk) { const float4 wv = *(const float4*)(Wfij + (kk) * 4); \
    f0 = fmaf((fv), wv.x, f0); f1 = fmaf((fv), wv.y, f1);                     \
    f2 = fmaf((fv), wv.z, f2); f3 = fmaf((fv), wv.w, f3); }
    FSTEP(q0.x, 0)  FSTEP(q0.y, 1)  FSTEP(q0.z, 2)  FSTEP(q0.w, 3)
    FSTEP(q1.x, 4)  FSTEP(q1.y, 5)  FSTEP(q1.z, 6)  FSTEP(q1.w, 7)
    FSTEP(q2.x, 8)  FSTEP(q2.y, 9)  FSTEP(q2.z, 10) FSTEP(q2.w, 11)
    FSTEP(q3.x, 12) FSTEP(q3.y, 13) FSTEP(q3.z, 14) FSTEP(q3.w, 15)
#undef FSTEP
    f0 = (f0 > 0.f) ? f0 : SLOPE * f0;
    f1 = (f1 > 0.f) ? f1 : SLOPE * f1;
    f2 = (f2 > 0.f) ? f2 : SLOPE * f2;
    f3 = (f3 > 0.f) ? f3 : SLOPE * f3;
    const float e0 = f0 * attn2[0], e1v = f1 * attn2[1];
    const float e2v_ = f2 * attn2[2], e3 = f3 * attn2[3];
    *(float4*)(e2 + (size_t)e * 4) = make_float4(e0, e1v, e2v_, e3);
    atomicMax(&m2[(size_t)d * 4 + 0], fenc(e0));
    atomicMax(&m2[(size_t)d * 4 + 1], fenc(e1v));
    atomicMax(&m2[(size_t)d * 4 + 2], fenc(e2v_));
    atomicMax(&m2[(size_t)d * 4 + 3], fenc(e3));
}

// ---- Pass G: layer-2 message passing. Wave per edge; lane = h*16 + c.
__global__ __launch_bounds__(256) void k_msg2(
    const int* __restrict__ src, const int* __restrict__ dst,
    const float* __restrict__ e2, const unsigned* __restrict__ m2,
    const float* __restrict__ s2, const float* __restrict__ ft2,
    float* __restrict__ out, int E)
{
    const int lane = threadIdx.x & 63;
    const int edge = blockIdx.x * 4 + (threadIdx.x >> 6);
    if (edge >= E) return;
    const int s = src[edge], d = dst[edge];
    const float4 ev = *(const float4*)(e2 + (size_t)edge * 4);
    const uint4  mv = *(const uint4*)(m2 + (size_t)d * 4);
    const float4 sv = *(const float4*)(s2 + (size_t)d * 4);
    const float c0 = __expf(ev.x - fdec(mv.x)) / sv.x;
    const float c1 = __expf(ev.y - fdec(mv.y)) / sv.y;
    const float c2 = __expf(ev.z - fdec(mv.z)) / sv.z;
    const float c3 = __expf(ev.w - fdec(mv.w)) / sv.w;
    const float coef = (lane < 16) ? c0 : (lane < 32) ? c1 : (lane < 48) ? c2 : c3;
    const float val = ft2[(size_t)s * 64 + lane] * coef;
    atomicAdd(out + (size_t)d * 64 + lane, val);
}

extern "C" void kernel_launch(void* const* d_in, const int* in_sizes, int n_in,
                              void* d_out, int out_size, void* d_ws, size_t ws_size,
                              hipStream_t stream)
{
    const float* nfeat  = (const float*)d_in[0];
    const float* efeat  = (const float*)d_in[1];
    const int*   src    = (const int*)d_in[2];
    const int*   dst    = (const int*)d_in[3];
    const float* W1ni   = (const float*)d_in[4];
    const float* W1fij  = (const float*)d_in[5];
    const float* W1nj   = (const float*)d_in[6];
    const float* b1e    = (const float*)d_in[7];
    const float* W1node = (const float*)d_in[8];
    const float* b1n    = (const float*)d_in[9];
    const float* attn1  = (const float*)d_in[10];
    const float* W2ni   = (const float*)d_in[11];
    const float* W2fij  = (const float*)d_in[12];
    const float* W2nj   = (const float*)d_in[13];
    const float* b2e    = (const float*)d_in[14];
    const float* W2node = (const float*)d_in[15];
    const float* b2n    = (const float*)d_in[16];
    const float* attn2  = (const float*)d_in[17];
    const int n = in_sizes[0] / 128;
    const int E = in_sizes[2];
    float* out = (float*)d_out;

    char* w = (char*)d_ws;
    auto alloc = [&](size_t bytes) {
        char* p = w; w += (bytes + 255) & ~(size_t)255; return p;
    };
    float*    ft1  = (float*)alloc((size_t)n * 256 * 4);
    float*    fe   = (float*)alloc((size_t)E * 16 * 4);
    float*    out1 = (float*)alloc((size_t)n * 256 * 4);
    float*    e1   = (float*)alloc((size_t)E * 4 * 4);   // reused as e2
    float*    fni  = (float*)alloc((size_t)n * 64 * 4);  // reused as ft2
    float*    fnj  = (float*)alloc((size_t)n * 64 * 4);  // reused as hbuf
    unsigned* m1   = (unsigned*)alloc((size_t)n * 4 * 4);
    float*    s1   = (float*)alloc((size_t)n * 4 * 4);
    unsigned* m2   = (unsigned*)alloc((size_t)n * 4 * 4);
    float*    s2   = (float*)alloc((size_t)n * 4 * 4);
    float*    fni2 = (float*)alloc((size_t)n * 4 * 4);
    float*    fnj2 = (float*)alloc((size_t)n * 4 * 4);
    float* e2   = e1;   // e1 dead after k_msg1
    float* ft2  = fni;  // fni dead after k_edge1
    float* hbuf = fnj;  // fnj dead after k_edge1

    hipMemsetAsync(m1, 0, (size_t)n * 4 * 4, stream);
    hipMemsetAsync(s1, 0, (size_t)n * 4 * 4, stream);
    hipMemsetAsync(m2, 0, (size_t)n * 4 * 4, stream);
    hipMemsetAsync(s2, 0, (size_t)n * 4 * 4, stream);
    hipMemsetAsync(out1, 0, (size_t)n * 256 * 4, stream);
    hipMemsetAsync(out, 0, (size_t)n * 64 * 4, stream);

    k_nodeproj1<<<n, 256, 0, stream>>>(nfeat, W1ni, W1nj, W1node, b1n, fni, fnj, ft1);
    k_edge1<<<(E + 3) / 4, 256, 0, stream>>>(efeat, src, dst, W1fij, b1e, attn1,
                                             fni, fnj, e1, fe, m1, E);
    k_soft<<<(E * 4 + 255) / 256, 256, 0, stream>>>(dst, e1, m1, s1, E);
    k_msg1<<<(E + 3) / 4, 256, 0, stream>>>(src, dst, e1, m1, s1, ft1, out1, E);
    k_headavg1<<<(n * 64 + 255) / 256, 256, 0, stream>>>(out1, hbuf, n);
    k_nodeproj2<<<(n + 3) / 4, 256, 0, stream>>>(hbuf, W2ni, W2nj, W2node, b2n,
                                                 fni2, fnj2, ft2, n);
    k_edge2<<<(E + 255) / 256, 256, 0, stream>>>(fe, src, dst, W2fij, b2e, attn2,
                                                 fni2, fnj2, e2, m2, E);
    k_soft<<<(E * 4 + 255) / 256, 256, 0, stream>>>(dst, e2, m2, s2, E);
    k_msg2<<<(E + 3) / 4, 256, 0, stream>>>(src, dst, e2, m2, s2, ft2, out, E);
}

// Round 2
// 2138.834 us; speedup vs baseline: 1.6992x; 1.6992x over previous
//
#include <hip/hip_runtime.h>

#define SLOPE 0.2f
#define NEG_INF (-3.0e38f)

// ============================ CSR build =====================================

__global__ __launch_bounds__(256) void k_deg(
    const int* __restrict__ dst, int* __restrict__ deg, int E)
{
    const int e = blockIdx.x * 256 + threadIdx.x;
    if (e < E) atomicAdd(&deg[dst[e]], 1);
}

// single-block exclusive scan (1024 threads, 4 elems/thread/iter)
__global__ __launch_bounds__(1024) void k_scan(
    const int* __restrict__ deg, int* __restrict__ offs,
    int* __restrict__ cursor, int n)
{
    __shared__ int wsum[16];
    __shared__ int carry_s;
    if (threadIdx.x == 0) carry_s = 0;
    __syncthreads();
    const int lane = threadIdx.x & 63, wid = threadIdx.x >> 6;
    for (int base = 0; base < n; base += 4096) {
        const int i0 = base + threadIdx.x * 4;
        const int d0 = (i0     < n) ? deg[i0]     : 0;
        const int d1 = (i0 + 1 < n) ? deg[i0 + 1] : 0;
        const int d2 = (i0 + 2 < n) ? deg[i0 + 2] : 0;
        const int d3 = (i0 + 3 < n) ? deg[i0 + 3] : 0;
        const int v = d0 + d1 + d2 + d3;
        int x = v;
        for (int dd = 1; dd < 64; dd <<= 1) {
            int y = __shfl_up(x, dd, 64);
            if (lane >= dd) x += y;
        }
        if (lane == 63) wsum[wid] = x;
        __syncthreads();
        if (threadIdx.x < 16) {
            int t = wsum[threadIdx.x];
            for (int dd = 1; dd < 16; dd <<= 1) {
                int y = __shfl_up(t, dd, 64);
                if ((int)threadIdx.x >= dd) t += y;
            }
            wsum[threadIdx.x] = t;
        }
        __syncthreads();
        int excl = carry_s + (wid ? wsum[wid - 1] : 0) + (x - v);
        if (i0     < n) { offs[i0]     = excl; cursor[i0]     = excl; }
        excl += d0;
        if (i0 + 1 < n) { offs[i0 + 1] = excl; cursor[i0 + 1] = excl; }
        excl += d1;
        if (i0 + 2 < n) { offs[i0 + 2] = excl; cursor[i0 + 2] = excl; }
        excl += d2;
        if (i0 + 3 < n) { offs[i0 + 3] = excl; cursor[i0 + 3] = excl; }
        __syncthreads();
        if (threadIdx.x == 0) carry_s += wsum[15];
        __syncthreads();
    }
    if (threadIdx.x == 0) offs[n] = carry_s;
}

// se[pos] = (src, edge_id) sorted by dst
__global__ __launch_bounds__(256) void k_scatter(
    const int* __restrict__ src, const int* __restrict__ dst,
    int* __restrict__ cursor, int2* __restrict__ se, int E)
{
    const int e = blockIdx.x * 256 + threadIdx.x;
    if (e >= E) return;
    const int p = atomicAdd(&cursor[dst[e]], 1);
    se[p] = make_int2(src[e], e);
}

// ======================= layer-1 node projections ===========================
__global__ __launch_bounds__(256) void k_nodeproj1(
    const float* __restrict__ nf, const float* __restrict__ Wni,
    const float* __restrict__ Wnj, const float* __restrict__ Wnode,
    const float* __restrict__ bnode,
    float* __restrict__ fni, float* __restrict__ fnj, float* __restrict__ ft1)
{
    __shared__ float s[128];
    const int node = blockIdx.x;
    const int t = threadIdx.x;
    if (t < 128) s[t] = nf[(size_t)node * 128 + t];
    __syncthreads();
    float acc = bnode[t];
#pragma unroll 4
    for (int k = 0; k < 128; k++) acc = fmaf(s[k], Wnode[k * 256 + t], acc);
    ft1[(size_t)node * 256 + t] = acc;
    if (t < 128) {
        const float* __restrict__ W = (t < 64) ? Wni : Wnj;
        const int j = t & 63;
        float a = 0.f;
#pragma unroll 4
        for (int k = 0; k < 128; k++) a = fmaf(s[k], W[k * 64 + j], a);
        if (t < 64) fni[(size_t)node * 64 + j] = a;
        else        fnj[(size_t)node * 64 + j] = a;
    }
}

// =========================== layer-1 edge pass ==============================
// wave per edge: f = fni[src] + ef@Wfij + fnj[dst] + b; leaky;
// e1[e][h] = dot(f_h, attn_h); fe[e][c] = 0.25*sum_h max(f,0)
__global__ __launch_bounds__(256) void k_edge1(
    const float* __restrict__ ef, const int* __restrict__ src,
    const int* __restrict__ dst, const float* __restrict__ Wfij,
    const float* __restrict__ bedge, const float* __restrict__ attn,
    const float* __restrict__ fni, const float* __restrict__ fnj,
    float* __restrict__ e1, float* __restrict__ fe, int E)
{
    const int lane = threadIdx.x & 63;
    const int edge = blockIdx.x * 4 + (threadIdx.x >> 6);
    if (edge >= E) return;
    const int s = src[edge], d = dst[edge];
    float v = (lane < 32) ? ef[(size_t)edge * 32 + lane] : 0.f;
    float f = fni[(size_t)s * 64 + lane] + fnj[(size_t)d * 64 + lane] + bedge[lane];
#pragma unroll
    for (int k = 0; k < 32; k++)
        f = fmaf(__shfl(v, k, 64), Wfij[k * 64 + lane], f);
    const float fl = (f > 0.f) ? f : SLOPE * f;
    const int h = lane >> 4;
    float p = fl * attn[h * 16 + (lane & 15)];
    p += __shfl_xor(p, 1, 64);
    p += __shfl_xor(p, 2, 64);
    p += __shfl_xor(p, 4, 64);
    p += __shfl_xor(p, 8, 64);
    if ((lane & 15) == 0) e1[(size_t)edge * 4 + h] = p;
    float r = fmaxf(fl, 0.f);
    r += __shfl_xor(r, 16, 64);
    r += __shfl_xor(r, 32, 64);
    if (lane < 16) fe[(size_t)edge * 16 + lane] = 0.25f * r;
}

// ================= layer-1 fused softmax + message + relu-mean ==============
// wave per node; lane = feature channel c (0..63); acc[h] per lane.
__global__ __launch_bounds__(256) void k_node1(
    const int* __restrict__ offs, const int2* __restrict__ se,
    const float* __restrict__ e1, const float* __restrict__ ft1,
    float* __restrict__ hbuf, int n)
{
    const int lane = threadIdx.x & 63;
    const int node = blockIdx.x * 4 + (threadIdx.x >> 6);
    if (node >= n) return;
    const int beg = offs[node], end = offs[node + 1];

    // phase 1: per-head max over edges
    float m0 = NEG_INF, m1 = NEG_INF, m2 = NEG_INF, m3 = NEG_INF;
    for (int p = beg + lane; p < end; p += 64) {
        const float4 ev = *(const float4*)(e1 + (size_t)se[p].y * 4);
        m0 = fmaxf(m0, ev.x); m1 = fmaxf(m1, ev.y);
        m2 = fmaxf(m2, ev.z); m3 = fmaxf(m3, ev.w);
    }
#pragma unroll
    for (int dd = 1; dd < 64; dd <<= 1) {
        m0 = fmaxf(m0, __shfl_xor(m0, dd, 64));
        m1 = fmaxf(m1, __shfl_xor(m1, dd, 64));
        m2 = fmaxf(m2, __shfl_xor(m2, dd, 64));
        m3 = fmaxf(m3, __shfl_xor(m3, dd, 64));
    }
    // phase 2: per-head exp-sum
    float s0 = 0.f, s1 = 0.f, s2 = 0.f, s3 = 0.f;
    for (int p = beg + lane; p < end; p += 64) {
        const float4 ev = *(const float4*)(e1 + (size_t)se[p].y * 4);
        s0 += __expf(ev.x - m0); s1 += __expf(ev.y - m1);
        s2 += __expf(ev.z - m2); s3 += __expf(ev.w - m3);
    }
#pragma unroll
    for (int dd = 1; dd < 64; dd <<= 1) {
        s0 += __shfl_xor(s0, dd, 64);
        s1 += __shfl_xor(s1, dd, 64);
        s2 += __shfl_xor(s2, dd, 64);
        s3 += __shfl_xor(s3, dd, 64);
    }
    const float r0 = (s0 > 0.f) ? 1.f / s0 : 0.f;
    const float r1 = (s1 > 0.f) ? 1.f / s1 : 0.f;
    const float r2 = (s2 > 0.f) ? 1.f / s2 : 0.f;
    const float r3 = (s3 > 0.f) ? 1.f / s3 : 0.f;
    // phase 3: accumulate attention-weighted source features
    float a0 = 0.f, a1 = 0.f, a2 = 0.f, a3 = 0.f;
    for (int p = beg; p < end; ++p) {
        const int2 sp = se[p];
        const float4 ev = *(const float4*)(e1 + (size_t)sp.y * 4);  // bcast
        const float c0 = __expf(ev.x - m0) * r0;
        const float c1 = __expf(ev.y - m1) * r1;
        const float c2 = __expf(ev.z - m2) * r2;
        const float c3 = __expf(ev.w - m3) * r3;
        const float* __restrict__ f = ft1 + (size_t)sp.x * 256 + lane;
        a0 = fmaf(c0, f[0],   a0);
        a1 = fmaf(c1, f[64],  a1);
        a2 = fmaf(c2, f[128], a2);
        a3 = fmaf(c3, f[192], a3);
    }
    hbuf[(size_t)node * 64 + lane] =
        0.25f * (fmaxf(a0, 0.f) + fmaxf(a1, 0.f) + fmaxf(a2, 0.f) + fmaxf(a3, 0.f));
}

// ======================= layer-2 node projections ===========================
__global__ __launch_bounds__(256) void k_nodeproj2(
    const float* __restrict__ hbuf, const float* __restrict__ Wni,
    const float* __restrict__ Wnj, const float* __restrict__ Wnode,
    const float* __restrict__ bnode,
    float* __restrict__ fni2, float* __restrict__ fnj2, float* __restrict__ ft2,
    int n)
{
    __shared__ float sh[4][64];
    const int lane = threadIdx.x & 63, w = threadIdx.x >> 6;
    const int node = blockIdx.x * 4 + w;
    const int nc = (node < n) ? node : (n - 1);
    const float v = hbuf[(size_t)nc * 64 + lane];
    sh[w][lane] = v;
    __syncthreads();
    float acc = bnode[lane];
#pragma unroll 4
    for (int k = 0; k < 64; k++) acc = fmaf(sh[w][k], Wnode[k * 64 + lane], acc);
    float pi[4], pj[4];
#pragma unroll
    for (int h = 0; h < 4; h++) { pi[h] = v * Wni[lane * 4 + h]; pj[h] = v * Wnj[lane * 4 + h]; }
#pragma unroll
    for (int mk = 1; mk < 64; mk <<= 1) {
#pragma unroll
        for (int h = 0; h < 4; h++) {
            pi[h] += __shfl_xor(pi[h], mk, 64);
            pj[h] += __shfl_xor(pj[h], mk, 64);
        }
    }
    if (node < n) {
        ft2[(size_t)node * 64 + lane] = acc;
        if (lane == 0) {
            *(float4*)(fni2 + (size_t)node * 4) = make_float4(pi[0], pi[1], pi[2], pi[3]);
            *(float4*)(fnj2 + (size_t)node * 4) = make_float4(pj[0], pj[1], pj[2], pj[3]);
        }
    }
}

// =========================== layer-2 edge pass ==============================
__global__ __launch_bounds__(256) void k_edge2(
    const float* __restrict__ fe, const int* __restrict__ src,
    const int* __restrict__ dst, const float* __restrict__ Wfij,
    const float* __restrict__ bedge, const float* __restrict__ attn2,
    const float* __restrict__ fni2, const float* __restrict__ fnj2,
    float* __restrict__ e2, int E)
{
    const int e = blockIdx.x * 256 + threadIdx.x;
    if (e >= E) return;
    const int s = src[e], d = dst[e];
    const float4 a = *(const float4*)(fni2 + (size_t)s * 4);
    const float4 b = *(const float4*)(fnj2 + (size_t)d * 4);
    float f0 = a.x + b.x + bedge[0];
    float f1 = a.y + b.y + bedge[1];
    float f2 = a.z + b.z + bedge[2];
    float f3 = a.w + b.w + bedge[3];
    const float4* fer = (const float4*)(fe + (size_t)e * 16);
    const float4 q0 = fer[0], q1 = fer[1], q2 = fer[2], q3 = fer[3];
#define FSTEP(fv, kk) { const float4 wv = *(const float4*)(Wfij + (kk) * 4); \
    f0 = fmaf((fv), wv.x, f0); f1 = fmaf((fv), wv.y, f1);                     \
    f2 = fmaf((fv), wv.z, f2); f3 = fmaf((fv), wv.w, f3); }
    FSTEP(q0.x, 0)  FSTEP(q0.y, 1)  FSTEP(q0.z, 2)  FSTEP(q0.w, 3)
    FSTEP(q1.x, 4)  FSTEP(q1.y, 5)  FSTEP(q1.z, 6)  FSTEP(q1.w, 7)
    FSTEP(q2.x, 8)  FSTEP(q2.y, 9)  FSTEP(q2.z, 10) FSTEP(q2.w, 11)
    FSTEP(q3.x, 12) FSTEP(q3.y, 13) FSTEP(q3.z, 14) FSTEP(q3.w, 15)
#undef FSTEP
    f0 = (f0 > 0.f) ? f0 : SLOPE * f0;
    f1 = (f1 > 0.f) ? f1 : SLOPE * f1;
    f2 = (f2 > 0.f) ? f2 : SLOPE * f2;
    f3 = (f3 > 0.f) ? f3 : SLOPE * f3;
    *(float4*)(e2 + (size_t)e * 4) =
        make_float4(f0 * attn2[0], f1 * attn2[1], f2 * attn2[2], f3 * attn2[3]);
}

// ================= layer-2 fused softmax + message passing ==================
// wave per node; lane = h*16 + c; writes d_out directly.
__global__ __launch_bounds__(256) void k_node2(
    const int* __restrict__ offs, const int2* __restrict__ se,
    const float* __restrict__ e2, const float* __restrict__ ft2,
    float* __restrict__ out, int n)
{
    const int lane = threadIdx.x & 63;
    const int node = blockIdx.x * 4 + (threadIdx.x >> 6);
    if (node >= n) return;
    const int beg = offs[node], end = offs[node + 1];

    float m0 = NEG_INF, m1 = NEG_INF, m2 = NEG_INF, m3 = NEG_INF;
    for (int p = beg + lane; p < end; p += 64) {
        const float4 ev = *(const float4*)(e2 + (size_t)se[p].y * 4);
        m0 = fmaxf(m0, ev.x); m1 = fmaxf(m1, ev.y);
        m2 = fmaxf(m2, ev.z); m3 = fmaxf(m3, ev.w);
    }
#pragma unroll
    for (int dd = 1; dd < 64; dd <<= 1) {
        m0 = fmaxf(m0, __shfl_xor(m0, dd, 64));
        m1 = fmaxf(m1, __shfl_xor(m1, dd, 64));
        m2 = fmaxf(m2, __shfl_xor(m2, dd, 64));
        m3 = fmaxf(m3, __shfl_xor(m3, dd, 64));
    }
    float s0 = 0.f, s1 = 0.f, s2 = 0.f, s3 = 0.f;
    for (int p = beg + lane; p < end; p += 64) {
        const float4 ev = *(const float4*)(e2 + (size_t)se[p].y * 4);
        s0 += __expf(ev.x - m0); s1 += __expf(ev.y - m1);
        s2 += __expf(ev.z - m2); s3 += __expf(ev.w - m3);
    }
#pragma unroll
    for (int dd = 1; dd < 64; dd <<= 1) {
        s0 += __shfl_xor(s0, dd, 64);
        s1 += __shfl_xor(s1, dd, 64);
        s2 += __shfl_xor(s2, dd, 64);
        s3 += __shfl_xor(s3, dd, 64);
    }
    const int h = lane >> 4;
    const float mh = (h == 0) ? m0 : (h == 1) ? m1 : (h == 2) ? m2 : m3;
    float sh = (h == 0) ? s0 : (h == 1) ? s1 : (h == 2) ? s2 : s3;
    const float rh = (sh > 0.f) ? 1.f / sh : 0.f;
    float acc = 0.f;
    for (int p = beg; p < end; ++p) {
        const int2 sp = se[p];
        const float ev = e2[(size_t)sp.y * 4 + h];
        const float c = __expf(ev - mh) * rh;
        acc = fmaf(c, ft2[(size_t)sp.x * 64 + lane], acc);
    }
    out[(size_t)node * 64 + lane] = acc;
}

extern "C" void kernel_launch(void* const* d_in, const int* in_sizes, int n_in,
                              void* d_out, int out_size, void* d_ws, size_t ws_size,
                              hipStream_t stream)
{
    const float* nfeat  = (const float*)d_in[0];
    const float* efeat  = (const float*)d_in[1];
    const int*   src    = (const int*)d_in[2];
    const int*   dst    = (const int*)d_in[3];
    const float* W1ni   = (const float*)d_in[4];
    const float* W1fij  = (const float*)d_in[5];
    const float* W1nj   = (const float*)d_in[6];
    const float* b1e    = (const float*)d_in[7];
    const float* W1node = (const float*)d_in[8];
    const float* b1n    = (const float*)d_in[9];
    const float* attn1  = (const float*)d_in[10];
    const float* W2ni   = (const float*)d_in[11];
    const float* W2fij  = (const float*)d_in[12];
    const float* W2nj   = (const float*)d_in[13];
    const float* b2e    = (const float*)d_in[14];
    const float* W2node = (const float*)d_in[15];
    const float* b2n    = (const float*)d_in[16];
    const float* attn2  = (const float*)d_in[17];
    const int n = in_sizes[0] / 128;
    const int E = in_sizes[2];
    float* out = (float*)d_out;

    char* w = (char*)d_ws;
    auto alloc = [&](size_t bytes) {
        char* p = w; w += (bytes + 255) & ~(size_t)255; return p;
    };
    float* ft1  = (float*)alloc((size_t)n * 256 * 4);
    float* fe   = (float*)alloc((size_t)E * 16 * 4);
    float* e1   = (float*)alloc((size_t)E * 4 * 4);    // reused as e2
    float* fni  = (float*)alloc((size_t)n * 64 * 4);   // reused as hbuf
    float* fnj  = (float*)alloc((size_t)n * 64 * 4);   // reused as ft2
    int*   deg  = (int*)alloc((size_t)n * 4);
    int*   offs = (int*)alloc((size_t)(n + 1) * 4);
    int*   curs = (int*)alloc((size_t)n * 4);
    int2*  se   = (int2*)alloc((size_t)E * 8);
    float* fni2 = (float*)alloc((size_t)n * 4 * 4);
    float* fnj2 = (float*)alloc((size_t)n * 4 * 4);
    float* e2   = e1;   // e1 dead after k_node1
    float* hbuf = fni;  // fni dead after k_edge1
    float* ft2  = fnj;  // fnj dead after k_edge1

    // ---- CSR build (amortized over both layers)
    hipMemsetAsync(deg, 0, (size_t)n * 4, stream);
    k_deg<<<(E + 255) / 256, 256, 0, stream>>>(dst, deg, E);
    k_scan<<<1, 1024, 0, stream>>>(deg, offs, curs, n);
    k_scatter<<<(E + 255) / 256, 256, 0, stream>>>(src, dst, curs, se, E);

    // ---- layer 1
    k_nodeproj1<<<n, 256, 0, stream>>>(nfeat, W1ni, W1nj, W1node, b1n, fni, fnj, ft1);
    k_edge1<<<(E + 3) / 4, 256, 0, stream>>>(efeat, src, dst, W1fij, b1e, attn1,
                                             fni, fnj, e1, fe, E);
    k_node1<<<(n + 3) / 4, 256, 0, stream>>>(offs, se, e1, ft1, hbuf, n);

    // ---- layer 2
    k_nodeproj2<<<(n + 3) / 4, 256, 0, stream>>>(hbuf, W2ni, W2nj, W2node, b2n,
                                                 fni2, fnj2, ft2, n);
    k_edge2<<<(E + 255) / 256, 256, 0, stream>>>(fe, src, dst, W2fij, b2e, attn2,
                                                 fni2, fnj2, e2, E);
    k_node2<<<(n + 3) / 4, 256, 0, stream>>>(offs, se, e2, ft2, out, n);
}

// Round 3
// 1652.017 us; speedup vs baseline: 2.1999x; 1.2947x over previous
//
#include <hip/hip_runtime.h>

#define SLOPE 0.2f
#define NEG_INF (-3.0e38f)
#define NPB 16  // nodes per block in k_nodeproj1

// ============================ CSR build =====================================

__global__ __launch_bounds__(256) void k_deg(
    const int* __restrict__ dst, int* __restrict__ deg, int E)
{
    const int e = blockIdx.x * 256 + threadIdx.x;
    if (e < E) atomicAdd(&deg[dst[e]], 1);
}

// single-block exclusive scan (1024 threads, 4 elems/thread/iter)
__global__ __launch_bounds__(1024) void k_scan(
    const int* __restrict__ deg, int* __restrict__ offs,
    int* __restrict__ cursor, int n)
{
    __shared__ int wsum[16];
    __shared__ int carry_s;
    if (threadIdx.x == 0) carry_s = 0;
    __syncthreads();
    const int lane = threadIdx.x & 63, wid = threadIdx.x >> 6;
    for (int base = 0; base < n; base += 4096) {
        const int i0 = base + threadIdx.x * 4;
        const int d0 = (i0     < n) ? deg[i0]     : 0;
        const int d1 = (i0 + 1 < n) ? deg[i0 + 1] : 0;
        const int d2 = (i0 + 2 < n) ? deg[i0 + 2] : 0;
        const int d3 = (i0 + 3 < n) ? deg[i0 + 3] : 0;
        const int v = d0 + d1 + d2 + d3;
        int x = v;
        for (int dd = 1; dd < 64; dd <<= 1) {
            int y = __shfl_up(x, dd, 64);
            if (lane >= dd) x += y;
        }
        if (lane == 63) wsum[wid] = x;
        __syncthreads();
        if (threadIdx.x < 16) {
            int t = wsum[threadIdx.x];
            for (int dd = 1; dd < 16; dd <<= 1) {
                int y = __shfl_up(t, dd, 64);
                if ((int)threadIdx.x >= dd) t += y;
            }
            wsum[threadIdx.x] = t;
        }
        __syncthreads();
        int excl = carry_s + (wid ? wsum[wid - 1] : 0) + (x - v);
        if (i0     < n) { offs[i0]     = excl; cursor[i0]     = excl; }
        excl += d0;
        if (i0 + 1 < n) { offs[i0 + 1] = excl; cursor[i0 + 1] = excl; }
        excl += d1;
        if (i0 + 2 < n) { offs[i0 + 2] = excl; cursor[i0 + 2] = excl; }
        excl += d2;
        if (i0 + 3 < n) { offs[i0 + 3] = excl; cursor[i0 + 3] = excl; }
        __syncthreads();
        if (threadIdx.x == 0) carry_s += wsum[15];
        __syncthreads();
    }
    if (threadIdx.x == 0) offs[n] = carry_s;
}

// srcs[p] = src of the edge in CSR slot p; pos[e] = CSR slot of edge e
__global__ __launch_bounds__(256) void k_scatter(
    const int* __restrict__ src, const int* __restrict__ dst,
    int* __restrict__ cursor, int* __restrict__ srcs, int* __restrict__ pos,
    int E)
{
    const int e = blockIdx.x * 256 + threadIdx.x;
    if (e >= E) return;
    const int p = atomicAdd(&cursor[dst[e]], 1);
    srcs[p] = src[e];
    pos[e] = p;
}

// ======================= layer-1 node projections ===========================
// 16 nodes/block; k outermost; weights read once per block (L1-hot).
__global__ __launch_bounds__(256) void k_nodeproj1(
    const float* __restrict__ nf, const float* __restrict__ Wni,
    const float* __restrict__ Wnj, const float* __restrict__ Wnode,
    const float* __restrict__ bnode,
    float* __restrict__ fni, float* __restrict__ fnj, float* __restrict__ ft1,
    int n)
{
    __shared__ float s[128][20];  // [k][node_local], pad 20 for banks + f4 align
    const int t = threadIdx.x;
    const int node0 = blockIdx.x * NPB;
    for (int i = 0; i < 8; i++) {
        const int idx = i * 256 + t;           // 0..2047
        const int k = idx & 127, nl = idx >> 7;
        const int node = node0 + nl;
        s[k][nl] = (node < n) ? nf[(size_t)node * 128 + k] : 0.f;
    }
    __syncthreads();
    const int lane = t & 63;
    const int w4 = (t >> 6) * 4;  // this wave's 4 local nodes
    const float4 b4 = *(const float4*)&bnode[lane * 4];
    float an[4][4];               // ft1 accum [node][col4]
    float ai[4], aj[4];
#pragma unroll
    for (int nn = 0; nn < 4; nn++) {
        an[nn][0] = b4.x; an[nn][1] = b4.y; an[nn][2] = b4.z; an[nn][3] = b4.w;
        ai[nn] = 0.f; aj[nn] = 0.f;
    }
#pragma unroll 4
    for (int k = 0; k < 128; k++) {
        const float4 wn = *(const float4*)&Wnode[(size_t)k * 256 + lane * 4];
        const float wi = Wni[(size_t)k * 64 + lane];
        const float wj = Wnj[(size_t)k * 64 + lane];
        const float4 sv = *(const float4*)&s[k][w4];
        const float sl[4] = {sv.x, sv.y, sv.z, sv.w};
#pragma unroll
        for (int nn = 0; nn < 4; nn++) {
            an[nn][0] = fmaf(wn.x, sl[nn], an[nn][0]);
            an[nn][1] = fmaf(wn.y, sl[nn], an[nn][1]);
            an[nn][2] = fmaf(wn.z, sl[nn], an[nn][2]);
            an[nn][3] = fmaf(wn.w, sl[nn], an[nn][3]);
            ai[nn] = fmaf(wi, sl[nn], ai[nn]);
            aj[nn] = fmaf(wj, sl[nn], aj[nn]);
        }
    }
#pragma unroll
    for (int nn = 0; nn < 4; nn++) {
        const int node = node0 + w4 + nn;
        if (node < n) {
            *(float4*)&ft1[(size_t)node * 256 + lane * 4] =
                make_float4(an[nn][0], an[nn][1], an[nn][2], an[nn][3]);
            fni[(size_t)node * 64 + lane] = ai[nn];
            fnj[(size_t)node * 64 + lane] = aj[nn];
        }
    }
}

// =========================== layer-1 edge pass ==============================
// wave per edge; writes e1 in CSR-sorted order (e1s[pos[e]]).
__global__ __launch_bounds__(256) void k_edge1(
    const float* __restrict__ ef, const int* __restrict__ src,
    const int* __restrict__ dst, const int* __restrict__ pos,
    const float* __restrict__ Wfij, const float* __restrict__ bedge,
    const float* __restrict__ attn, const float* __restrict__ fni,
    const float* __restrict__ fnj,
    float* __restrict__ e1s, float* __restrict__ fe, int E)
{
    const int lane = threadIdx.x & 63;
    const int edge = blockIdx.x * 4 + (threadIdx.x >> 6);
    if (edge >= E) return;
    const int s = src[edge], d = dst[edge];
    float v = (lane < 32) ? ef[(size_t)edge * 32 + lane] : 0.f;
    float f = fni[(size_t)s * 64 + lane] + fnj[(size_t)d * 64 + lane] + bedge[lane];
#pragma unroll
    for (int k = 0; k < 32; k++)
        f = fmaf(__shfl(v, k, 64), Wfij[k * 64 + lane], f);
    const float fl = (f > 0.f) ? f : SLOPE * f;
    const int h = lane >> 4;
    float p = fl * attn[h * 16 + (lane & 15)];
    p += __shfl_xor(p, 1, 64);
    p += __shfl_xor(p, 2, 64);
    p += __shfl_xor(p, 4, 64);
    p += __shfl_xor(p, 8, 64);
    if ((lane & 15) == 0) e1s[(size_t)pos[edge] * 4 + h] = p;
    float r = fmaxf(fl, 0.f);
    r += __shfl_xor(r, 16, 64);
    r += __shfl_xor(r, 32, 64);
    if (lane < 16) fe[(size_t)edge * 16 + lane] = 0.25f * r;
}

// ================= layer-1 fused softmax + message + relu-mean ==============
__global__ __launch_bounds__(256) void k_node1(
    const int* __restrict__ offs, const int* __restrict__ srcs,
    const float* __restrict__ e1s, const float* __restrict__ ft1,
    float* __restrict__ hbuf, int n)
{
    const int lane = threadIdx.x & 63;
    const int node = blockIdx.x * 4 + (threadIdx.x >> 6);
    if (node >= n) return;
    const int beg = offs[node], end = offs[node + 1];

    float m0 = NEG_INF, m1 = NEG_INF, m2 = NEG_INF, m3 = NEG_INF;
    for (int p = beg + lane; p < end; p += 64) {
        const float4 ev = *(const float4*)(e1s + (size_t)p * 4);
        m0 = fmaxf(m0, ev.x); m1 = fmaxf(m1, ev.y);
        m2 = fmaxf(m2, ev.z); m3 = fmaxf(m3, ev.w);
    }
#pragma unroll
    for (int dd = 1; dd < 64; dd <<= 1) {
        m0 = fmaxf(m0, __shfl_xor(m0, dd, 64));
        m1 = fmaxf(m1, __shfl_xor(m1, dd, 64));
        m2 = fmaxf(m2, __shfl_xor(m2, dd, 64));
        m3 = fmaxf(m3, __shfl_xor(m3, dd, 64));
    }
    float s0 = 0.f, s1 = 0.f, s2 = 0.f, s3 = 0.f;
    for (int p = beg + lane; p < end; p += 64) {
        const float4 ev = *(const float4*)(e1s + (size_t)p * 4);
        s0 += __expf(ev.x - m0); s1 += __expf(ev.y - m1);
        s2 += __expf(ev.z - m2); s3 += __expf(ev.w - m3);
    }
#pragma unroll
    for (int dd = 1; dd < 64; dd <<= 1) {
        s0 += __shfl_xor(s0, dd, 64);
        s1 += __shfl_xor(s1, dd, 64);
        s2 += __shfl_xor(s2, dd, 64);
        s3 += __shfl_xor(s3, dd, 64);
    }
    const float r0 = (s0 > 0.f) ? 1.f / s0 : 0.f;
    const float r1 = (s1 > 0.f) ? 1.f / s1 : 0.f;
    const float r2 = (s2 > 0.f) ? 1.f / s2 : 0.f;
    const float r3 = (s3 > 0.f) ? 1.f / s3 : 0.f;
    float a0 = 0.f, a1 = 0.f, a2 = 0.f, a3 = 0.f;
    for (int p = beg; p < end; ++p) {
        const float4 ev = *(const float4*)(e1s + (size_t)p * 4);  // bcast
        const int sp = srcs[p];
        const float c0 = __expf(ev.x - m0) * r0;
        const float c1 = __expf(ev.y - m1) * r1;
        const float c2 = __expf(ev.z - m2) * r2;
        const float c3 = __expf(ev.w - m3) * r3;
        const float* __restrict__ f = ft1 + (size_t)sp * 256 + lane;
        a0 = fmaf(c0, f[0],   a0);
        a1 = fmaf(c1, f[64],  a1);
        a2 = fmaf(c2, f[128], a2);
        a3 = fmaf(c3, f[192], a3);
    }
    hbuf[(size_t)node * 64 + lane] =
        0.25f * (fmaxf(a0, 0.f) + fmaxf(a1, 0.f) + fmaxf(a2, 0.f) + fmaxf(a3, 0.f));
}

// ======================= layer-2 node projections ===========================
__global__ __launch_bounds__(256) void k_nodeproj2(
    const float* __restrict__ hbuf, const float* __restrict__ Wni,
    const float* __restrict__ Wnj, const float* __restrict__ Wnode,
    const float* __restrict__ bnode,
    float* __restrict__ fni2, float* __restrict__ fnj2, float* __restrict__ ft2,
    int n)
{
    __shared__ float sh[4][64];
    const int lane = threadIdx.x & 63, w = threadIdx.x >> 6;
    const int node = blockIdx.x * 4 + w;
    const int nc = (node < n) ? node : (n - 1);
    const float v = hbuf[(size_t)nc * 64 + lane];
    sh[w][lane] = v;
    __syncthreads();
    float acc = bnode[lane];
#pragma unroll 4
    for (int k = 0; k < 64; k++) acc = fmaf(sh[w][k], Wnode[k * 64 + lane], acc);
    float pi[4], pj[4];
#pragma unroll
    for (int h = 0; h < 4; h++) { pi[h] = v * Wni[lane * 4 + h]; pj[h] = v * Wnj[lane * 4 + h]; }
#pragma unroll
    for (int mk = 1; mk < 64; mk <<= 1) {
#pragma unroll
        for (int h = 0; h < 4; h++) {
            pi[h] += __shfl_xor(pi[h], mk, 64);
            pj[h] += __shfl_xor(pj[h], mk, 64);
        }
    }
    if (node < n) {
        ft2[(size_t)node * 64 + lane] = acc;
        if (lane == 0) {
            *(float4*)(fni2 + (size_t)node * 4) = make_float4(pi[0], pi[1], pi[2], pi[3]);
            *(float4*)(fnj2 + (size_t)node * 4) = make_float4(pj[0], pj[1], pj[2], pj[3]);
        }
    }
}

// =========================== layer-2 edge pass ==============================
__global__ __launch_bounds__(256) void k_edge2(
    const float* __restrict__ fe, const int* __restrict__ src,
    const int* __restrict__ dst, const int* __restrict__ pos,
    const float* __restrict__ Wfij, const float* __restrict__ bedge,
    const float* __restrict__ attn2, const float* __restrict__ fni2,
    const float* __restrict__ fnj2, float* __restrict__ e2s, int E)
{
    const int e = blockIdx.x * 256 + threadIdx.x;
    if (e >= E) return;
    const int s = src[e], d = dst[e];
    const float4 a = *(const float4*)(fni2 + (size_t)s * 4);
    const float4 b = *(const float4*)(fnj2 + (size_t)d * 4);
    float f0 = a.x + b.x + bedge[0];
    float f1 = a.y + b.y + bedge[1];
    float f2 = a.z + b.z + bedge[2];
    float f3 = a.w + b.w + bedge[3];
    const float4* fer = (const float4*)(fe + (size_t)e * 16);
    const float4 q0 = fer[0], q1 = fer[1], q2 = fer[2], q3 = fer[3];
#define FSTEP(fv, kk) { const float4 wv = *(const float4*)(Wfij + (kk) * 4); \
    f0 = fmaf((fv), wv.x, f0); f1 = fmaf((fv), wv.y, f1);                     \
    f2 = fmaf((fv), wv.z, f2); f3 = fmaf((fv), wv.w, f3); }
    FSTEP(q0.x, 0)  FSTEP(q0.y, 1)  FSTEP(q0.z, 2)  FSTEP(q0.w, 3)
    FSTEP(q1.x, 4)  FSTEP(q1.y, 5)  FSTEP(q1.z, 6)  FSTEP(q1.w, 7)
    FSTEP(q2.x, 8)  FSTEP(q2.y, 9)  FSTEP(q2.z, 10) FSTEP(q2.w, 11)
    FSTEP(q3.x, 12) FSTEP(q3.y, 13) FSTEP(q3.z, 14) FSTEP(q3.w, 15)
#undef FSTEP
    f0 = (f0 > 0.f) ? f0 : SLOPE * f0;
    f1 = (f1 > 0.f) ? f1 : SLOPE * f1;
    f2 = (f2 > 0.f) ? f2 : SLOPE * f2;
    f3 = (f3 > 0.f) ? f3 : SLOPE * f3;
    *(float4*)(e2s + (size_t)pos[e] * 4) =
        make_float4(f0 * attn2[0], f1 * attn2[1], f2 * attn2[2], f3 * attn2[3]);
}

// ================= layer-2 fused softmax + message passing ==================
__global__ __launch_bounds__(256) void k_node2(
    const int* __restrict__ offs, const int* __restrict__ srcs,
    const float* __restrict__ e2s, const float* __restrict__ ft2,
    float* __restrict__ out, int n)
{
    const int lane = threadIdx.x & 63;
    const int node = blockIdx.x * 4 + (threadIdx.x >> 6);
    if (node >= n) return;
    const int beg = offs[node], end = offs[node + 1];

    float m0 = NEG_INF, m1 = NEG_INF, m2 = NEG_INF, m3 = NEG_INF;
    for (int p = beg + lane; p < end; p += 64) {
        const float4 ev = *(const float4*)(e2s + (size_t)p * 4);
        m0 = fmaxf(m0, ev.x); m1 = fmaxf(m1, ev.y);
        m2 = fmaxf(m2, ev.z); m3 = fmaxf(m3, ev.w);
    }
#pragma unroll
    for (int dd = 1; dd < 64; dd <<= 1) {
        m0 = fmaxf(m0, __shfl_xor(m0, dd, 64));
        m1 = fmaxf(m1, __shfl_xor(m1, dd, 64));
        m2 = fmaxf(m2, __shfl_xor(m2, dd, 64));
        m3 = fmaxf(m3, __shfl_xor(m3, dd, 64));
    }
    float s0 = 0.f, s1 = 0.f, s2 = 0.f, s3 = 0.f;
    for (int p = beg + lane; p < end; p += 64) {
        const float4 ev = *(const float4*)(e2s + (size_t)p * 4);
        s0 += __expf(ev.x - m0); s1 += __expf(ev.y - m1);
        s2 += __expf(ev.z - m2); s3 += __expf(ev.w - m3);
    }
#pragma unroll
    for (int dd = 1; dd < 64; dd <<= 1) {
        s0 += __shfl_xor(s0, dd, 64);
        s1 += __shfl_xor(s1, dd, 64);
        s2 += __shfl_xor(s2, dd, 64);
        s3 += __shfl_xor(s3, dd, 64);
    }
    const int h = lane >> 4;
    const float mh = (h == 0) ? m0 : (h == 1) ? m1 : (h == 2) ? m2 : m3;
    float sh = (h == 0) ? s0 : (h == 1) ? s1 : (h == 2) ? s2 : s3;
    const float rh = (sh > 0.f) ? 1.f / sh : 0.f;
    float acc = 0.f;
    for (int p = beg; p < end; ++p) {
        const float ev = e2s[(size_t)p * 4 + h];
        const int sp = srcs[p];
        const float c = __expf(ev - mh) * rh;
        acc = fmaf(c, ft2[(size_t)sp * 64 + lane], acc);
    }
    out[(size_t)node * 64 + lane] = acc;
}

extern "C" void kernel_launch(void* const* d_in, const int* in_sizes, int n_in,
                              void* d_out, int out_size, void* d_ws, size_t ws_size,
                              hipStream_t stream)
{
    const float* nfeat  = (const float*)d_in[0];
    const float* efeat  = (const float*)d_in[1];
    const int*   src    = (const int*)d_in[2];
    const int*   dst    = (const int*)d_in[3];
    const float* W1ni   = (const float*)d_in[4];
    const float* W1fij  = (const float*)d_in[5];
    const float* W1nj   = (const float*)d_in[6];
    const float* b1e    = (const float*)d_in[7];
    const float* W1node = (const float*)d_in[8];
    const float* b1n    = (const float*)d_in[9];
    const float* attn1  = (const float*)d_in[10];
    const float* W2ni   = (const float*)d_in[11];
    const float* W2fij  = (const float*)d_in[12];
    const float* W2nj   = (const float*)d_in[13];
    const float* b2e    = (const float*)d_in[14];
    const float* W2node = (const float*)d_in[15];
    const float* b2n    = (const float*)d_in[16];
    const float* attn2  = (const float*)d_in[17];
    const int n = in_sizes[0] / 128;
    const int E = in_sizes[2];
    float* out = (float*)d_out;

    char* w = (char*)d_ws;
    auto alloc = [&](size_t bytes) {
        char* p = w; w += (bytes + 255) & ~(size_t)255; return p;
    };
    float* ft1  = (float*)alloc((size_t)n * 256 * 4);
    float* fe   = (float*)alloc((size_t)E * 16 * 4);
    float* e1s  = (float*)alloc((size_t)E * 4 * 4);    // CSR-sorted; reused as e2s
    float* fni  = (float*)alloc((size_t)n * 64 * 4);   // reused as hbuf
    float* fnj  = (float*)alloc((size_t)n * 64 * 4);   // reused as ft2
    int*   deg  = (int*)alloc((size_t)n * 4);
    int*   offs = (int*)alloc((size_t)(n + 1) * 4);
    int*   curs = (int*)alloc((size_t)n * 4);
    int*   srcs = (int*)alloc((size_t)E * 4);
    int*   pos  = (int*)alloc((size_t)E * 4);
    float* fni2 = (float*)alloc((size_t)n * 4 * 4);
    float* fnj2 = (float*)alloc((size_t)n * 4 * 4);
    float* e2s  = e1s;  // e1s dead after k_node1
    float* hbuf = fni;  // fni dead after k_edge1
    float* ft2  = fnj;  // fnj dead after k_edge1

    // ---- CSR build (amortized over both layers)
    hipMemsetAsync(deg, 0, (size_t)n * 4, stream);
    k_deg<<<(E + 255) / 256, 256, 0, stream>>>(dst, deg, E);
    k_scan<<<1, 1024, 0, stream>>>(deg, offs, curs, n);
    k_scatter<<<(E + 255) / 256, 256, 0, stream>>>(src, dst, curs, srcs, pos, E);

    // ---- layer 1
    k_nodeproj1<<<(n + NPB - 1) / NPB, 256, 0, stream>>>(
        nfeat, W1ni, W1nj, W1node, b1n, fni, fnj, ft1, n);
    k_edge1<<<(E + 3) / 4, 256, 0, stream>>>(efeat, src, dst, pos, W1fij, b1e,
                                             attn1, fni, fnj, e1s, fe, E);
    k_node1<<<(n + 3) / 4, 256, 0, stream>>>(offs, srcs, e1s, ft1, hbuf, n);

    // ---- layer 2
    k_nodeproj2<<<(n + 3) / 4, 256, 0, stream>>>(hbuf, W2ni, W2nj, W2node, b2n,
                                                 fni2, fnj2, ft2, n);
    k_edge2<<<(E + 255) / 256, 256, 0, stream>>>(fe, src, dst, pos, W2fij, b2e,
                                                 attn2, fni2, fnj2, e2s, E);
    k_node2<<<(n + 3) / 4, 256, 0, stream>>>(offs, srcs, e2s, ft2, out, n);
}